// Round 7
// baseline (953.578 us; speedup 1.0000x reference)
//
#include <hip/hip_runtime.h>
#include <hip/hip_bf16.h>

#define N_NODES 100000
#define N_EDGES 3200000
#define FEAT 256
#define HIDDEN 32
#define EMBED 16
#define TR 64        // rows per gemm1 block
#define PAD 4        // LDS row pad (floats)
#define CAP 64       // bucket capacity per node (Poisson(32); P(deg>64)~4e-6/node)
#define OCAP 8192    // overflow list capacity

// ---------------- init: cnt=0, overflow cursor=0 ----------------
__global__ void k_init0(int* __restrict__ cnt, int* __restrict__ ocur) {
    int i = blockIdx.x * blockDim.x + threadIdx.x;
    if (i < N_NODES) cnt[i] = 0;
    if (i == 0) *ocur = 0;
}

// ---------------- bucket build: one returning atomic per edge ----------------
__global__ void k_fillb(const int* __restrict__ col, int* __restrict__ cnt,
                        int* __restrict__ bkt, int* __restrict__ ocur,
                        int* __restrict__ olist) {
    int e = blockIdx.x * blockDim.x + threadIdx.x;
    if (e < N_EDGES) {
        int c = col[e];
        int slot = atomicAdd(&cnt[c], 1);
        if (slot < CAP) bkt[c * CAP + slot] = e;
        else { int p = atomicAdd(ocur, 1); if (p < OCAP) olist[p] = e; }
    }
}

// ---------------- weighted degree via gather (no atomics) ----------------
__global__ void k_deg(const int* __restrict__ cnt, const int* __restrict__ bkt,
                      const float* __restrict__ ew, float* __restrict__ deg) {
    int i = blockIdx.x * blockDim.x + threadIdx.x;
    if (i < N_NODES) {
        int n = min(cnt[i], CAP);
        float s = 1.0f;  // self loop
        const int* bp = bkt + i * CAP;
        for (int j = 0; j < n; ++j) s += ew[bp[j]];
        deg[i] = s;
    }
}

__global__ void k_degover(const int* __restrict__ ocur, const int* __restrict__ olist,
                          const int* __restrict__ col, const float* __restrict__ ew,
                          float* __restrict__ deg) {
    int p = blockIdx.x * blockDim.x + threadIdx.x;
    int n = min(*ocur, OCAP);
    if (p < n) { int e = olist[p]; unsafeAtomicAdd(&deg[col[e]], ew[e]); }
}

__global__ void k_dis(float* __restrict__ deg) {
    int i = blockIdx.x * blockDim.x + threadIdx.x;
    if (i < N_NODES) {
        float d = deg[i];
        deg[i] = (d > 0.0f) ? rsqrtf(d) : 0.0f;
    }
}

// ---------------- layer 1 GEMM: h = x @ W1^T, LDS-tiled (unchanged) ----------------
__global__ __launch_bounds__(256) void k_gemm1(
        const float* __restrict__ x, const float* __restrict__ W1,
        float* __restrict__ h) {
    __shared__ float sx[TR][FEAT + PAD];
    __shared__ float sw[HIDDEN][FEAT + PAD];

    const int tid = threadIdx.x;
    const size_t base = (size_t)blockIdx.x * TR;
    const float4* x4 = (const float4*)x;
    const float4* w4 = (const float4*)W1;

    for (int i = tid; i < HIDDEN * (FEAT / 4); i += 256) {
        int f = i >> 6, kq = i & 63;
        *(float4*)&sw[f][kq * 4] = w4[f * 64 + kq];
    }
    for (int i = tid; i < TR * (FEAT / 4); i += 256) {
        int r = i >> 6, kq = i & 63;
        float4 v = make_float4(0.f, 0.f, 0.f, 0.f);
        if (base + r < N_NODES) v = x4[(base + r) * (FEAT / 4) + kq];
        *(float4*)&sx[r][kq * 4] = v;
    }
    __syncthreads();

    const int r0 = tid >> 3;
    const int c0 = tid & 7;
    float acc[2][4] = {{0.f, 0.f, 0.f, 0.f}, {0.f, 0.f, 0.f, 0.f}};

#pragma unroll 4
    for (int kq = 0; kq < FEAT / 4; ++kq) {
        float4 xa = *(const float4*)&sx[r0][kq * 4];
        float4 xb = *(const float4*)&sx[r0 + 32][kq * 4];
#pragma unroll
        for (int j = 0; j < 4; ++j) {
            float4 wv = *(const float4*)&sw[c0 + 8 * j][kq * 4];
            acc[0][j] += xa.x * wv.x + xa.y * wv.y + xa.z * wv.z + xa.w * wv.w;
            acc[1][j] += xb.x * wv.x + xb.y * wv.y + xb.z * wv.z + xb.w * wv.w;
        }
    }

    size_t ra = base + r0, rb = base + r0 + 32;
    if (ra < N_NODES) {
#pragma unroll
        for (int j = 0; j < 4; ++j) h[ra * HIDDEN + c0 + 8 * j] = acc[0][j];
    }
    if (rb < N_NODES) {
#pragma unroll
        for (int j = 0; j < 4; ++j) h[rb * HIDDEN + c0 + 8 * j] = acc[1][j];
    }
}

// ---- layer 1 gather: out1[c] = d*sum(h[src]*dis[src]*ew) + h[c]*d^2 + b1 ----
__global__ __launch_bounds__(256) void k_gather1(
        const int* __restrict__ cnt, const int* __restrict__ bkt,
        const int* __restrict__ row, const float* __restrict__ ew,
        const float* __restrict__ h, const float* __restrict__ dis,
        const float* __restrict__ b1, float* __restrict__ out1) {
    int t = blockIdx.x * blockDim.x + threadIdx.x;
    int node = t >> 3;
    if (node >= N_NODES) return;
    int og = t & 7;

    float d = dis[node];
    float d2 = d * d;
    float4 self = *(const float4*)(h + (size_t)node * HIDDEN + og * 4);
    float4 bv = *(const float4*)(b1 + og * 4);
    float4 acc = make_float4(0.f, 0.f, 0.f, 0.f);

    int n = min(cnt[node], CAP);
    const int* bp = bkt + node * CAP;
    for (int j = 0; j < n; ++j) {
        int e = bp[j];
        int r = row[e];
        float w = dis[r] * ew[e];
        float4 hv = *(const float4*)(h + (size_t)r * HIDDEN + og * 4);
        acc.x += hv.x * w; acc.y += hv.y * w; acc.z += hv.z * w; acc.w += hv.w * w;
    }
    float4 res = make_float4(acc.x * d + self.x * d2 + bv.x,
                             acc.y * d + self.y * d2 + bv.y,
                             acc.z * d + self.z * d2 + bv.z,
                             acc.w * d + self.w * d2 + bv.w);
    *(float4*)(out1 + (size_t)node * HIDDEN + og * 4) = res;
}

__global__ void k_over1(const int* __restrict__ ocur, const int* __restrict__ olist,
                        const int* __restrict__ row, const int* __restrict__ col,
                        const float* __restrict__ ew, const float* __restrict__ dis,
                        const float* __restrict__ h, float* __restrict__ out1) {
    int p = blockIdx.x * blockDim.x + threadIdx.x;
    int n = min(*ocur, OCAP);
    if (p < n) {
        int e = olist[p];
        int r = row[e], c = col[e];
        float w = dis[r] * ew[e] * dis[c];
        for (int f = 0; f < HIDDEN; ++f)
            unsafeAtomicAdd(&out1[(size_t)c * HIDDEN + f], h[(size_t)r * HIDDEN + f] * w);
    }
}

// ---------------- layer 2 GEMM: h2 = relu(out1) @ W2^T (unchanged) ----------------
__global__ void k_gemm2(const float* __restrict__ out1, const float* __restrict__ W2,
                        float* __restrict__ h2) {
    int t = blockIdx.x * blockDim.x + threadIdx.x;
    int i = t >> 4;
    if (i >= N_NODES) return;
    int f = t & 15;
    const float* r = out1 + (size_t)i * HIDDEN;
    const float* w = W2 + f * HIDDEN;
    float acc = 0.f;
#pragma unroll
    for (int k = 0; k < HIDDEN; ++k) acc += fmaxf(r[k], 0.f) * w[k];
    h2[(size_t)i * EMBED + f] = acc;
}

// ---- layer 2 gather ----
__global__ __launch_bounds__(256) void k_gather2(
        const int* __restrict__ cnt, const int* __restrict__ bkt,
        const int* __restrict__ row, const float* __restrict__ ew,
        const float* __restrict__ h2, const float* __restrict__ dis,
        const float* __restrict__ b2, float* __restrict__ out) {
    int t = blockIdx.x * blockDim.x + threadIdx.x;
    int node = t >> 2;
    if (node >= N_NODES) return;
    int og = t & 3;

    float d = dis[node];
    float d2 = d * d;
    float4 self = *(const float4*)(h2 + (size_t)node * EMBED + og * 4);
    float4 bv = *(const float4*)(b2 + og * 4);
    float4 acc = make_float4(0.f, 0.f, 0.f, 0.f);

    int n = min(cnt[node], CAP);
    const int* bp = bkt + node * CAP;
    for (int j = 0; j < n; ++j) {
        int e = bp[j];
        int r = row[e];
        float w = dis[r] * ew[e];
        float4 hv = *(const float4*)(h2 + (size_t)r * EMBED + og * 4);
        acc.x += hv.x * w; acc.y += hv.y * w; acc.z += hv.z * w; acc.w += hv.w * w;
    }
    float4 res = make_float4(acc.x * d + self.x * d2 + bv.x,
                             acc.y * d + self.y * d2 + bv.y,
                             acc.z * d + self.z * d2 + bv.z,
                             acc.w * d + self.w * d2 + bv.w);
    *(float4*)(out + (size_t)node * EMBED + og * 4) = res;
}

__global__ void k_over2(const int* __restrict__ ocur, const int* __restrict__ olist,
                        const int* __restrict__ row, const int* __restrict__ col,
                        const float* __restrict__ ew, const float* __restrict__ dis,
                        const float* __restrict__ h2, float* __restrict__ out) {
    int p = blockIdx.x * blockDim.x + threadIdx.x;
    int n = min(*ocur, OCAP);
    if (p < n) {
        int e = olist[p];
        int r = row[e], c = col[e];
        float w = dis[r] * ew[e] * dis[c];
        for (int f = 0; f < EMBED; ++f)
            unsafeAtomicAdd(&out[(size_t)c * EMBED + f], h2[(size_t)r * EMBED + f] * w);
    }
}

extern "C" void kernel_launch(void* const* d_in, const int* in_sizes, int n_in,
                              void* d_out, int out_size, void* d_ws, size_t ws_size,
                              hipStream_t stream) {
    const float* x  = (const float*)d_in[0];
    const int*   ei = (const int*)d_in[1];  // [2, E] int32
    const float* ew = (const float*)d_in[2];
    const float* W1 = (const float*)d_in[3];
    const float* b1 = (const float*)d_in[4];
    const float* W2 = (const float*)d_in[5];
    const float* b2 = (const float*)d_in[6];
    float* out = (float*)d_out;

    const int* row = ei;            // source
    const int* col = ei + N_EDGES;  // target

    // ws (4B units): dis[N] cnt[N] ocur[4] olist[OCAP] bkt[N*CAP] h[32N] out1[32N]  ~52 MB
    float* dis   = (float*)d_ws;
    int*   cnt   = (int*)(dis + N_NODES);
    int*   ocur  = cnt + N_NODES;
    int*   olist = ocur + 4;
    int*   bkt   = olist + OCAP;
    float* h     = (float*)(bkt + (size_t)N_NODES * CAP);  // 16B-aligned
    float* out1  = h + (size_t)N_NODES * HIDDEN;
    float* h2    = h;  // alias: h dead after k_gather1

    const int B = 256;
    const int gN = (N_NODES + B - 1) / B;
    const int gE = (N_EDGES + B - 1) / B;
    const int gO = (OCAP + B - 1) / B;

    k_init0<<<gN, B, 0, stream>>>(cnt, ocur);
    k_fillb<<<gE, B, 0, stream>>>(col, cnt, bkt, ocur, olist);
    k_deg<<<gN, B, 0, stream>>>(cnt, bkt, ew, dis);
    k_degover<<<gO, B, 0, stream>>>(ocur, olist, col, ew, dis);
    k_dis<<<gN, B, 0, stream>>>(dis);
    k_gemm1<<<(N_NODES + TR - 1) / TR, B, 0, stream>>>(x, W1, h);
    k_gather1<<<(N_NODES * 8 + B - 1) / B, B, 0, stream>>>(cnt, bkt, row, ew, h, dis, b1, out1);
    k_over1<<<gO, B, 0, stream>>>(ocur, olist, row, col, ew, dis, h, out1);
    k_gemm2<<<(N_NODES * 16 + B - 1) / B, B, 0, stream>>>(out1, W2, h2);
    k_gather2<<<(N_NODES * 4 + B - 1) / B, B, 0, stream>>>(cnt, bkt, row, ew, h2, dis, b2, out);
    k_over2<<<gO, B, 0, stream>>>(ocur, olist, row, col, ew, dis, h2, out);
}

// Round 8
// 427.893 us; speedup vs baseline: 2.2285x; 2.2285x over previous
//
#include <hip/hip_runtime.h>
#include <hip/hip_bf16.h>

#define N_NODES 100000
#define N_EDGES 3200000
#define FEAT 256
#define HIDDEN 32
#define EMBED 16
#define TR 64                                  // rows per gemm1 block
#define PAD 4                                  // LDS row pad (floats)
#define NPB 128                                // nodes per bin
#define NBIN ((N_NODES + NPB - 1) / NPB)       // 782
#define NBLK 1024                              // partition blocks
#define EPB ((N_EDGES + NBLK - 1) / NBLK)      // 3125 edges per block
#define CAPB 4608                              // bin capacity (mean 4096 + 8 sigma)
#define OCAP 8192                              // overflow list capacity

// ---------------- zero: binCnt, overflow cursor ----------------
__global__ void k_zero(int* __restrict__ binCnt, int* __restrict__ ocur) {
    int i = blockIdx.x * blockDim.x + threadIdx.x;
    if (i < NBIN) binCnt[i] = 0;
    if (i == 0) *ocur = 0;
}

// ---------------- partition edges into node-range bins ----------------
// Per block: LDS hist -> ONE returning global atomic per (block,bin) -> write
// edges {(lcol<<17)|src, ew_bits} into bin regions. Overflow (straddle CAPB)
// goes exact to olist (statistically empty: P(bin>mean+8sd) ~ 1e-13).
__global__ __launch_bounds__(256) void k_part(
        const int* __restrict__ row, const int* __restrict__ col,
        const float* __restrict__ ew, int* __restrict__ binCnt,
        int2* __restrict__ binned, int* __restrict__ ocur, int* __restrict__ olist) {
    __shared__ int sh[NBIN];   // hist, then base
    __shared__ int sc[NBIN];   // running cursor
    const int tid = threadIdx.x;
    for (int i = tid; i < NBIN; i += 256) sh[i] = 0;
    __syncthreads();
    const int e0 = blockIdx.x * EPB, e1 = min(e0 + EPB, N_EDGES);
    for (int e = e0 + tid; e < e1; e += 256) atomicAdd(&sh[col[e] >> 7], 1);
    __syncthreads();
    for (int i = tid; i < NBIN; i += 256) {
        int n = sh[i];
        sh[i] = (n > 0) ? atomicAdd(&binCnt[i], n) : 0;
        sc[i] = 0;
    }
    __syncthreads();
    for (int e = e0 + tid; e < e1; e += 256) {
        int c = col[e], b = c >> 7;
        int s = sh[b] + atomicAdd(&sc[b], 1);
        if (s < CAPB)
            binned[(size_t)b * CAPB + s] =
                make_int2(((c & (NPB - 1)) << 17) | row[e], __float_as_int(ew[e]));
        else { int p = atomicAdd(ocur, 1); if (p < OCAP) olist[p] = e; }
    }
}

// ---------------- per-bin: group by node in-place, deg, off2 ----------------
// Stages the bin in LDS; per-node counts + weighted deg via LDS atomics;
// LDS scan; rewrites region as per-node CSR {src, ew}. No global atomics.
__global__ __launch_bounds__(256) void k_build(
        const int* __restrict__ binCnt, int2* __restrict__ binned,
        float* __restrict__ deg, int2* __restrict__ off2) {
    __shared__ int2 se[CAPB];                       // 36864 B
    __shared__ int scnt[NPB], spfx[NPB], scur[NPB];
    __shared__ float sdeg[NPB];
    const int bin = blockIdx.x, tid = threadIdx.x;
    const int n = min(binCnt[bin], CAPB);
    const size_t base = (size_t)bin * CAPB;

    for (int i = tid; i < NPB; i += 256) { scnt[i] = 0; sdeg[i] = 0.f; }
    __syncthreads();
    for (int i = tid; i < n; i += 256) {
        int2 v = binned[base + i];
        se[i] = v;
        int lc = v.x >> 17;
        atomicAdd(&scnt[lc], 1);
        atomicAdd(&sdeg[lc], __int_as_float(v.y));
    }
    __syncthreads();
    if (tid < NPB) spfx[tid] = scnt[tid];
    __syncthreads();
    for (int d = 1; d < NPB; d <<= 1) {
        int t = 0;
        if (tid < NPB && tid >= d) t = spfx[tid - d];
        __syncthreads();
        if (tid < NPB) spfx[tid] += t;
        __syncthreads();
    }
    if (tid < NPB) {
        int ex = spfx[tid] - scnt[tid];   // exclusive prefix
        scur[tid] = ex;
        int node = bin * NPB + tid;
        if (node < N_NODES) {
            off2[node] = make_int2((int)base + ex, scnt[tid]);
            deg[node] = sdeg[tid] + 1.0f;  // + self loop
        }
    }
    __syncthreads();
    for (int i = tid; i < n; i += 256) {
        int2 v = se[i];
        int lc = v.x >> 17;
        int s = atomicAdd(&scur[lc], 1);   // LDS atomic
        binned[base + s] = make_int2(v.x & 0x1FFFF, v.y);  // {src, ew}
    }
}

__global__ void k_degover(const int* __restrict__ ocur, const int* __restrict__ olist,
                          const int* __restrict__ col, const float* __restrict__ ew,
                          float* __restrict__ deg) {
    int p = blockIdx.x * blockDim.x + threadIdx.x;
    int n = min(*ocur, OCAP);
    if (p < n) { int e = olist[p]; unsafeAtomicAdd(&deg[col[e]], ew[e]); }
}

__global__ void k_dis(float* __restrict__ deg) {
    int i = blockIdx.x * blockDim.x + threadIdx.x;
    if (i < N_NODES) {
        float d = deg[i];
        deg[i] = (d > 0.0f) ? rsqrtf(d) : 0.0f;
    }
}

// ---------------- fold dis[src] into csr weights in-place ----------------
__global__ void k_wnorm(const int* __restrict__ binCnt, int2* __restrict__ csr,
                        const float* __restrict__ dis) {
    int bin = blockIdx.x;
    int n = min(binCnt[bin], CAPB);
    size_t base = (size_t)bin * CAPB;
    for (int i = threadIdx.x; i < n; i += 256) {
        int2 v = csr[base + i];
        float w = __int_as_float(v.y) * dis[v.x];
        csr[base + i] = make_int2(v.x, __float_as_int(w));
    }
}

// ---------------- layer 1 GEMM: h = x @ W1^T, LDS-tiled (unchanged) ----------------
__global__ __launch_bounds__(256) void k_gemm1(
        const float* __restrict__ x, const float* __restrict__ W1,
        float* __restrict__ h) {
    __shared__ float sx[TR][FEAT + PAD];
    __shared__ float sw[HIDDEN][FEAT + PAD];

    const int tid = threadIdx.x;
    const size_t base = (size_t)blockIdx.x * TR;
    const float4* x4 = (const float4*)x;
    const float4* w4 = (const float4*)W1;

    for (int i = tid; i < HIDDEN * (FEAT / 4); i += 256) {
        int f = i >> 6, kq = i & 63;
        *(float4*)&sw[f][kq * 4] = w4[f * 64 + kq];
    }
    for (int i = tid; i < TR * (FEAT / 4); i += 256) {
        int r = i >> 6, kq = i & 63;
        float4 v = make_float4(0.f, 0.f, 0.f, 0.f);
        if (base + r < N_NODES) v = x4[(base + r) * (FEAT / 4) + kq];
        *(float4*)&sx[r][kq * 4] = v;
    }
    __syncthreads();

    const int r0 = tid >> 3;
    const int c0 = tid & 7;
    float acc[2][4] = {{0.f, 0.f, 0.f, 0.f}, {0.f, 0.f, 0.f, 0.f}};

#pragma unroll 4
    for (int kq = 0; kq < FEAT / 4; ++kq) {
        float4 xa = *(const float4*)&sx[r0][kq * 4];
        float4 xb = *(const float4*)&sx[r0 + 32][kq * 4];
#pragma unroll
        for (int j = 0; j < 4; ++j) {
            float4 wv = *(const float4*)&sw[c0 + 8 * j][kq * 4];
            acc[0][j] += xa.x * wv.x + xa.y * wv.y + xa.z * wv.z + xa.w * wv.w;
            acc[1][j] += xb.x * wv.x + xb.y * wv.y + xb.z * wv.z + xb.w * wv.w;
        }
    }

    size_t ra = base + r0, rb = base + r0 + 32;
    if (ra < N_NODES) {
#pragma unroll
        for (int j = 0; j < 4; ++j) h[ra * HIDDEN + c0 + 8 * j] = acc[0][j];
    }
    if (rb < N_NODES) {
#pragma unroll
        for (int j = 0; j < 4; ++j) h[rb * HIDDEN + c0 + 8 * j] = acc[1][j];
    }
}

// ---- layer 1 gather: out1[c] = d*sum(h[src]*w) + h[c]*d^2 + b1 ----
__global__ __launch_bounds__(256) void k_gather1(
        const int2* __restrict__ off2, const int2* __restrict__ csr,
        const float* __restrict__ h, const float* __restrict__ dis,
        const float* __restrict__ b1, float* __restrict__ out1) {
    int t = blockIdx.x * blockDim.x + threadIdx.x;
    int node = t >> 3;
    if (node >= N_NODES) return;
    int og = t & 7;

    float d = dis[node];
    float d2 = d * d;
    float4 self = *(const float4*)(h + (size_t)node * HIDDEN + og * 4);
    float4 bv = *(const float4*)(b1 + og * 4);
    float4 acc = make_float4(0.f, 0.f, 0.f, 0.f);

    int2 o = off2[node];
    for (int j = o.x; j < o.x + o.y; ++j) {
        int2 v = csr[j];
        float w = __int_as_float(v.y);
        float4 hv = *(const float4*)(h + (size_t)v.x * HIDDEN + og * 4);
        acc.x += hv.x * w; acc.y += hv.y * w; acc.z += hv.z * w; acc.w += hv.w * w;
    }
    *(float4*)(out1 + (size_t)node * HIDDEN + og * 4) =
        make_float4(acc.x * d + self.x * d2 + bv.x, acc.y * d + self.y * d2 + bv.y,
                    acc.z * d + self.z * d2 + bv.z, acc.w * d + self.w * d2 + bv.w);
}

__global__ void k_over1(const int* __restrict__ ocur, const int* __restrict__ olist,
                        const int* __restrict__ row, const int* __restrict__ col,
                        const float* __restrict__ ew, const float* __restrict__ dis,
                        const float* __restrict__ h, float* __restrict__ out1) {
    int p = blockIdx.x * blockDim.x + threadIdx.x;
    int n = min(*ocur, OCAP);
    if (p < n) {
        int e = olist[p];
        int r = row[e], c = col[e];
        float w = dis[r] * ew[e] * dis[c];
        for (int f = 0; f < HIDDEN; ++f)
            unsafeAtomicAdd(&out1[(size_t)c * HIDDEN + f], h[(size_t)r * HIDDEN + f] * w);
    }
}

// ---------------- layer 2 GEMM: h2 = relu(out1) @ W2^T (unchanged) ----------------
__global__ void k_gemm2(const float* __restrict__ out1, const float* __restrict__ W2,
                        float* __restrict__ h2) {
    int t = blockIdx.x * blockDim.x + threadIdx.x;
    int i = t >> 4;
    if (i >= N_NODES) return;
    int f = t & 15;
    const float* r = out1 + (size_t)i * HIDDEN;
    const float* w = W2 + f * HIDDEN;
    float acc = 0.f;
#pragma unroll
    for (int k = 0; k < HIDDEN; ++k) acc += fmaxf(r[k], 0.f) * w[k];
    h2[(size_t)i * EMBED + f] = acc;
}

// ---- layer 2 gather ----
__global__ __launch_bounds__(256) void k_gather2(
        const int2* __restrict__ off2, const int2* __restrict__ csr,
        const float* __restrict__ h2, const float* __restrict__ dis,
        const float* __restrict__ b2, float* __restrict__ out) {
    int t = blockIdx.x * blockDim.x + threadIdx.x;
    int node = t >> 2;
    if (node >= N_NODES) return;
    int og = t & 3;

    float d = dis[node];
    float d2 = d * d;
    float4 self = *(const float4*)(h2 + (size_t)node * EMBED + og * 4);
    float4 bv = *(const float4*)(b2 + og * 4);
    float4 acc = make_float4(0.f, 0.f, 0.f, 0.f);

    int2 o = off2[node];
    for (int j = o.x; j < o.x + o.y; ++j) {
        int2 v = csr[j];
        float w = __int_as_float(v.y);
        float4 hv = *(const float4*)(h2 + (size_t)v.x * EMBED + og * 4);
        acc.x += hv.x * w; acc.y += hv.y * w; acc.z += hv.z * w; acc.w += hv.w * w;
    }
    *(float4*)(out + (size_t)node * EMBED + og * 4) =
        make_float4(acc.x * d + self.x * d2 + bv.x, acc.y * d + self.y * d2 + bv.y,
                    acc.z * d + self.z * d2 + bv.z, acc.w * d + self.w * d2 + bv.w);
}

__global__ void k_over2(const int* __restrict__ ocur, const int* __restrict__ olist,
                        const int* __restrict__ row, const int* __restrict__ col,
                        const float* __restrict__ ew, const float* __restrict__ dis,
                        const float* __restrict__ h2, float* __restrict__ out) {
    int p = blockIdx.x * blockDim.x + threadIdx.x;
    int n = min(*ocur, OCAP);
    if (p < n) {
        int e = olist[p];
        int r = row[e], c = col[e];
        float w = dis[r] * ew[e] * dis[c];
        for (int f = 0; f < EMBED; ++f)
            unsafeAtomicAdd(&out[(size_t)c * EMBED + f], h2[(size_t)r * EMBED + f] * w);
    }
}

extern "C" void kernel_launch(void* const* d_in, const int* in_sizes, int n_in,
                              void* d_out, int out_size, void* d_ws, size_t ws_size,
                              hipStream_t stream) {
    const float* x  = (const float*)d_in[0];
    const int*   ei = (const int*)d_in[1];  // [2, E] int32
    const float* ew = (const float*)d_in[2];
    const float* W1 = (const float*)d_in[3];
    const float* b1 = (const float*)d_in[4];
    const float* W2 = (const float*)d_in[5];
    const float* b2 = (const float*)d_in[6];
    float* out = (float*)d_out;

    const int* row = ei;            // source
    const int* col = ei + N_EDGES;  // target

    // ws layout (8B-aligned base assumed):
    // off2[N] int2 | binned[NBIN*CAPB] int2 | deg[N] f32 | binCnt[NBIN] | ocur[2] |
    // olist[OCAP] | (16B align) h[32N] | out1[32N]   -- ~56 MB total
    int2*  off2   = (int2*)d_ws;
    int2*  binned = off2 + N_NODES;
    float* deg    = (float*)(binned + (size_t)NBIN * CAPB);
    int*   binCnt = (int*)(deg + N_NODES);
    int*   ocur   = binCnt + NBIN;
    int*   olist  = ocur + 2;
    size_t off_i  = (size_t)(olist + OCAP - (int*)d_ws);
    off_i = (off_i + 3) & ~(size_t)3;            // 16B align for float4
    float* h    = (float*)d_ws + off_i;
    float* out1 = h + (size_t)N_NODES * HIDDEN;
    float* h2   = h;  // alias: h dead after k_gather1

    const int B = 256;
    const int gN = (N_NODES + B - 1) / B;
    const int gO = (OCAP + B - 1) / B;

    k_zero<<<(NBIN + B - 1) / B, B, 0, stream>>>(binCnt, ocur);
    k_part<<<NBLK, B, 0, stream>>>(row, col, ew, binCnt, binned, ocur, olist);
    k_build<<<NBIN, B, 0, stream>>>(binCnt, binned, deg, off2);
    k_degover<<<gO, B, 0, stream>>>(ocur, olist, col, ew, deg);
    k_dis<<<gN, B, 0, stream>>>(deg);
    k_wnorm<<<NBIN, B, 0, stream>>>(binCnt, binned, deg);
    k_gemm1<<<(N_NODES + TR - 1) / TR, B, 0, stream>>>(x, W1, h);
    k_gather1<<<(N_NODES * 8 + B - 1) / B, B, 0, stream>>>(off2, binned, h, deg, b1, out1);
    k_over1<<<gO, B, 0, stream>>>(ocur, olist, row, col, ew, deg, h, out1);
    k_gemm2<<<(N_NODES * 16 + B - 1) / B, B, 0, stream>>>(out1, W2, h2);
    k_gather2<<<(N_NODES * 4 + B - 1) / B, B, 0, stream>>>(off2, binned, h2, deg, b2, out);
    k_over2<<<gO, B, 0, stream>>>(ocur, olist, row, col, ew, deg, h2, out);
}

// Round 9
// 389.448 us; speedup vs baseline: 2.4485x; 1.0987x over previous
//
#include <hip/hip_runtime.h>
#include <hip/hip_bf16.h>

#define N_NODES 100000
#define N_EDGES 3200000
#define FEAT 256
#define HIDDEN 32
#define EMBED 16
#define NPB 128                                // nodes per bin
#define NBIN ((N_NODES + NPB - 1) / NPB)       // 782
#define NBLK 1024                              // partition blocks
#define EPB ((N_EDGES + NBLK - 1) / NBLK)      // 3125 edges per block
#define CAPB 4608                              // bin capacity (mean 4096 + 8 sigma)
#define OCAP 8192                              // overflow list capacity
#define GR 128                                 // gemm1 tile rows
#define GS 68                                  // LDS row stride (floats): 16B-aligned, 4-bank shift

// ---------------- zero: binCnt, overflow cursor ----------------
__global__ void k_zero(int* __restrict__ binCnt, int* __restrict__ ocur) {
    int i = blockIdx.x * blockDim.x + threadIdx.x;
    if (i < NBIN) binCnt[i] = 0;
    if (i == 0) *ocur = 0;
}

// ---------------- partition edges into node-range bins ----------------
__global__ __launch_bounds__(256) void k_part(
        const int* __restrict__ row, const int* __restrict__ col,
        const float* __restrict__ ew, int* __restrict__ binCnt,
        int2* __restrict__ binned, int* __restrict__ ocur, int* __restrict__ olist) {
    __shared__ int sh[NBIN];   // hist, then base
    __shared__ int sc[NBIN];   // running cursor
    const int tid = threadIdx.x;
    for (int i = tid; i < NBIN; i += 256) sh[i] = 0;
    __syncthreads();
    const int e0 = blockIdx.x * EPB, e1 = min(e0 + EPB, N_EDGES);
    for (int e = e0 + tid; e < e1; e += 256) atomicAdd(&sh[col[e] >> 7], 1);
    __syncthreads();
    for (int i = tid; i < NBIN; i += 256) {
        int n = sh[i];
        sh[i] = (n > 0) ? atomicAdd(&binCnt[i], n) : 0;
        sc[i] = 0;
    }
    __syncthreads();
    for (int e = e0 + tid; e < e1; e += 256) {
        int c = col[e], b = c >> 7;
        int s = sh[b] + atomicAdd(&sc[b], 1);
        if (s < CAPB)
            binned[(size_t)b * CAPB + s] =
                make_int2(((c & (NPB - 1)) << 17) | row[e], __float_as_int(ew[e]));
        else { int p = atomicAdd(ocur, 1); if (p < OCAP) olist[p] = e; }
    }
}

// ---------------- per-bin: group by node in-place, deg, off2 ----------------
__global__ __launch_bounds__(256) void k_build(
        const int* __restrict__ binCnt, int2* __restrict__ binned,
        float* __restrict__ deg, int2* __restrict__ off2) {
    __shared__ int2 se[CAPB];
    __shared__ int scnt[NPB], spfx[NPB], scur[NPB];
    __shared__ float sdeg[NPB];
    const int bin = blockIdx.x, tid = threadIdx.x;
    const int n = min(binCnt[bin], CAPB);
    const size_t base = (size_t)bin * CAPB;

    for (int i = tid; i < NPB; i += 256) { scnt[i] = 0; sdeg[i] = 0.f; }
    __syncthreads();
    for (int i = tid; i < n; i += 256) {
        int2 v = binned[base + i];
        se[i] = v;
        int lc = v.x >> 17;
        atomicAdd(&scnt[lc], 1);
        atomicAdd(&sdeg[lc], __int_as_float(v.y));
    }
    __syncthreads();
    if (tid < NPB) spfx[tid] = scnt[tid];
    __syncthreads();
    for (int d = 1; d < NPB; d <<= 1) {
        int t = 0;
        if (tid < NPB && tid >= d) t = spfx[tid - d];
        __syncthreads();
        if (tid < NPB) spfx[tid] += t;
        __syncthreads();
    }
    if (tid < NPB) {
        int ex = spfx[tid] - scnt[tid];
        scur[tid] = ex;
        int node = bin * NPB + tid;
        if (node < N_NODES) {
            off2[node] = make_int2((int)base + ex, scnt[tid]);
            deg[node] = sdeg[tid] + 1.0f;  // + self loop
        }
    }
    __syncthreads();
    for (int i = tid; i < n; i += 256) {
        int2 v = se[i];
        int lc = v.x >> 17;
        int s = atomicAdd(&scur[lc], 1);   // LDS atomic
        binned[base + s] = make_int2(v.x & 0x1FFFF, v.y);  // {src, ew}
    }
}

__global__ void k_degover(const int* __restrict__ ocur, const int* __restrict__ olist,
                          const int* __restrict__ col, const float* __restrict__ ew,
                          float* __restrict__ deg) {
    int p = blockIdx.x * blockDim.x + threadIdx.x;
    int n = min(*ocur, OCAP);
    if (p < n) { int e = olist[p]; unsafeAtomicAdd(&deg[col[e]], ew[e]); }
}

__global__ void k_dis(float* __restrict__ deg) {
    int i = blockIdx.x * blockDim.x + threadIdx.x;
    if (i < N_NODES) {
        float d = deg[i];
        deg[i] = (d > 0.0f) ? rsqrtf(d) : 0.0f;
    }
}

// ---------------- fold dis[src] into csr weights in-place ----------------
__global__ void k_wnorm(const int* __restrict__ binCnt, int2* __restrict__ csr,
                        const float* __restrict__ dis) {
    int bin = blockIdx.x;
    int n = min(binCnt[bin], CAPB);
    size_t base = (size_t)bin * CAPB;
    for (int i = threadIdx.x; i < n; i += 256) {
        int2 v = csr[base + i];
        float w = __int_as_float(v.y) * dis[v.x];
        csr[base + i] = make_int2(v.x, __float_as_int(w));
    }
}

// ---------------- layer 1 GEMM: h = x @ W1^T ----------------
// K-phased (4 x 64), 128-row tile, 4x4 register micro-tile.
// LDS 43.5 KB -> 3 blocks/CU. Rows r0+32m, cols c0+8j: both LDS reads
// conflict-free (stride 68 floats = 4-bank shift, banks 4*r0/4*c0 distinct).
__global__ __launch_bounds__(256) void k_gemm1(
        const float* __restrict__ x, const float* __restrict__ W1,
        float* __restrict__ h) {
    __shared__ float sx[GR][GS];      // 34816 B
    __shared__ float sw[HIDDEN][GS];  //  8704 B

    const int tid = threadIdx.x;
    const size_t base = (size_t)blockIdx.x * GR;
    const float4* x4 = (const float4*)x;
    const float4* w4 = (const float4*)W1;

    const int r0 = tid >> 3;   // 0..31: rows r0 + 32m
    const int c0 = tid & 7;    // cols c0 + 8j
    float acc[4][4] = {};

#pragma unroll
    for (int p = 0; p < 4; ++p) {
        // stage x[0:128][p*64 + 0:64): 2048 float4, 8 per thread
        for (int i = tid; i < GR * 16; i += 256) {
            int r = i >> 4, kq = i & 15;
            float4 v = make_float4(0.f, 0.f, 0.f, 0.f);
            if (base + r < N_NODES) v = x4[(base + r) * 64 + p * 16 + kq];
            *(float4*)&sx[r][kq * 4] = v;
        }
        // stage W1[0:32][p*64 + 0:64): 512 float4, 2 per thread
        for (int i = tid; i < HIDDEN * 16; i += 256) {
            int f = i >> 4, kq = i & 15;
            *(float4*)&sw[f][kq * 4] = w4[f * 64 + p * 16 + kq];
        }
        __syncthreads();

#pragma unroll 4
        for (int kq = 0; kq < 16; ++kq) {
            float4 xa[4], wv[4];
#pragma unroll
            for (int m = 0; m < 4; ++m) xa[m] = *(const float4*)&sx[r0 + 32 * m][kq * 4];
#pragma unroll
            for (int j = 0; j < 4; ++j) wv[j] = *(const float4*)&sw[c0 + 8 * j][kq * 4];
#pragma unroll
            for (int m = 0; m < 4; ++m)
#pragma unroll
                for (int j = 0; j < 4; ++j)
                    acc[m][j] += xa[m].x * wv[j].x + xa[m].y * wv[j].y +
                                 xa[m].z * wv[j].z + xa[m].w * wv[j].w;
        }
        __syncthreads();
    }

#pragma unroll
    for (int m = 0; m < 4; ++m) {
        size_t r = base + r0 + 32 * m;
        if (r < N_NODES) {
#pragma unroll
            for (int j = 0; j < 4; ++j) h[r * HIDDEN + c0 + 8 * j] = acc[m][j];
        }
    }
}

// ---- layer 1 gather: out1[c] = d*sum(h[src]*w) + h[c]*d^2 + b1 ----
__global__ __launch_bounds__(256) void k_gather1(
        const int2* __restrict__ off2, const int2* __restrict__ csr,
        const float* __restrict__ h, const float* __restrict__ dis,
        const float* __restrict__ b1, float* __restrict__ out1) {
    int t = blockIdx.x * blockDim.x + threadIdx.x;
    int node = t >> 3;
    if (node >= N_NODES) return;
    int og = t & 7;

    float d = dis[node];
    float d2 = d * d;
    float4 self = *(const float4*)(h + (size_t)node * HIDDEN + og * 4);
    float4 bv = *(const float4*)(b1 + og * 4);
    float4 acc = make_float4(0.f, 0.f, 0.f, 0.f);

    int2 o = off2[node];
    for (int j = o.x; j < o.x + o.y; ++j) {
        int2 v = csr[j];
        float w = __int_as_float(v.y);
        float4 hv = *(const float4*)(h + (size_t)v.x * HIDDEN + og * 4);
        acc.x += hv.x * w; acc.y += hv.y * w; acc.z += hv.z * w; acc.w += hv.w * w;
    }
    *(float4*)(out1 + (size_t)node * HIDDEN + og * 4) =
        make_float4(acc.x * d + self.x * d2 + bv.x, acc.y * d + self.y * d2 + bv.y,
                    acc.z * d + self.z * d2 + bv.z, acc.w * d + self.w * d2 + bv.w);
}

__global__ void k_over1(const int* __restrict__ ocur, const int* __restrict__ olist,
                        const int* __restrict__ row, const int* __restrict__ col,
                        const float* __restrict__ ew, const float* __restrict__ dis,
                        const float* __restrict__ h, float* __restrict__ out1) {
    int p = blockIdx.x * blockDim.x + threadIdx.x;
    int n = min(*ocur, OCAP);
    if (p < n) {
        int e = olist[p];
        int r = row[e], c = col[e];
        float w = dis[r] * ew[e] * dis[c];
        for (int f = 0; f < HIDDEN; ++f)
            unsafeAtomicAdd(&out1[(size_t)c * HIDDEN + f], h[(size_t)r * HIDDEN + f] * w);
    }
}

// ---------------- layer 2 GEMM: h2 = relu(out1) @ W2^T ----------------
__global__ void k_gemm2(const float* __restrict__ out1, const float* __restrict__ W2,
                        float* __restrict__ h2) {
    int t = blockIdx.x * blockDim.x + threadIdx.x;
    int i = t >> 4;
    if (i >= N_NODES) return;
    int f = t & 15;
    const float* r = out1 + (size_t)i * HIDDEN;
    const float* w = W2 + f * HIDDEN;
    float acc = 0.f;
#pragma unroll
    for (int k = 0; k < HIDDEN; ++k) acc += fmaxf(r[k], 0.f) * w[k];
    h2[(size_t)i * EMBED + f] = acc;
}

// ---- layer 2 gather ----
__global__ __launch_bounds__(256) void k_gather2(
        const int2* __restrict__ off2, const int2* __restrict__ csr,
        const float* __restrict__ h2, const float* __restrict__ dis,
        const float* __restrict__ b2, float* __restrict__ out) {
    int t = blockIdx.x * blockDim.x + threadIdx.x;
    int node = t >> 2;
    if (node >= N_NODES) return;
    int og = t & 3;

    float d = dis[node];
    float d2 = d * d;
    float4 self = *(const float4*)(h2 + (size_t)node * EMBED + og * 4);
    float4 bv = *(const float4*)(b2 + og * 4);
    float4 acc = make_float4(0.f, 0.f, 0.f, 0.f);

    int2 o = off2[node];
    for (int j = o.x; j < o.x + o.y; ++j) {
        int2 v = csr[j];
        float w = __int_as_float(v.y);
        float4 hv = *(const float4*)(h2 + (size_t)v.x * EMBED + og * 4);
        acc.x += hv.x * w; acc.y += hv.y * w; acc.z += hv.z * w; acc.w += hv.w * w;
    }
    *(float4*)(out + (size_t)node * EMBED + og * 4) =
        make_float4(acc.x * d + self.x * d2 + bv.x, acc.y * d + self.y * d2 + bv.y,
                    acc.z * d + self.z * d2 + bv.z, acc.w * d + self.w * d2 + bv.w);
}

__global__ void k_over2(const int* __restrict__ ocur, const int* __restrict__ olist,
                        const int* __restrict__ row, const int* __restrict__ col,
                        const float* __restrict__ ew, const float* __restrict__ dis,
                        const float* __restrict__ h2, float* __restrict__ out) {
    int p = blockIdx.x * blockDim.x + threadIdx.x;
    int n = min(*ocur, OCAP);
    if (p < n) {
        int e = olist[p];
        int r = row[e], c = col[e];
        float w = dis[r] * ew[e] * dis[c];
        for (int f = 0; f < EMBED; ++f)
            unsafeAtomicAdd(&out[(size_t)c * EMBED + f], h2[(size_t)r * EMBED + f] * w);
    }
}

extern "C" void kernel_launch(void* const* d_in, const int* in_sizes, int n_in,
                              void* d_out, int out_size, void* d_ws, size_t ws_size,
                              hipStream_t stream) {
    const float* x  = (const float*)d_in[0];
    const int*   ei = (const int*)d_in[1];  // [2, E] int32
    const float* ew = (const float*)d_in[2];
    const float* W1 = (const float*)d_in[3];
    const float* b1 = (const float*)d_in[4];
    const float* W2 = (const float*)d_in[5];
    const float* b2 = (const float*)d_in[6];
    float* out = (float*)d_out;

    const int* row = ei;            // source
    const int* col = ei + N_EDGES;  // target

    // ws layout: off2[N] int2 | binned[NBIN*CAPB] int2 | deg[N] | binCnt[NBIN] |
    // ocur[2] | olist[OCAP] | (16B align) h[32N] | out1[32N]
    int2*  off2   = (int2*)d_ws;
    int2*  binned = off2 + N_NODES;
    float* deg    = (float*)(binned + (size_t)NBIN * CAPB);
    int*   binCnt = (int*)(deg + N_NODES);
    int*   ocur   = binCnt + NBIN;
    int*   olist  = ocur + 2;
    size_t off_i  = (size_t)(olist + OCAP - (int*)d_ws);
    off_i = (off_i + 3) & ~(size_t)3;            // 16B align
    float* h    = (float*)d_ws + off_i;
    float* out1 = h + (size_t)N_NODES * HIDDEN;
    float* h2   = h;  // alias: h dead after k_gather1

    const int B = 256;
    const int gN = (N_NODES + B - 1) / B;
    const int gO = (OCAP + B - 1) / B;

    k_zero<<<(NBIN + B - 1) / B, B, 0, stream>>>(binCnt, ocur);
    k_part<<<NBLK, B, 0, stream>>>(row, col, ew, binCnt, binned, ocur, olist);
    k_build<<<NBIN, B, 0, stream>>>(binCnt, binned, deg, off2);
    k_degover<<<gO, B, 0, stream>>>(ocur, olist, col, ew, deg);
    k_dis<<<gN, B, 0, stream>>>(deg);
    k_wnorm<<<NBIN, B, 0, stream>>>(binCnt, binned, deg);
    k_gemm1<<<(N_NODES + GR - 1) / GR, B, 0, stream>>>(x, W1, h);
    k_gather1<<<(N_NODES * 8 + B - 1) / B, B, 0, stream>>>(off2, binned, h, deg, b1, out1);
    k_over1<<<gO, B, 0, stream>>>(ocur, olist, row, col, ew, deg, h, out1);
    k_gemm2<<<(N_NODES * 16 + B - 1) / B, B, 0, stream>>>(out1, W2, h2);
    k_gather2<<<(N_NODES * 4 + B - 1) / B, B, 0, stream>>>(off2, binned, h2, deg, b2, out);
    k_over2<<<gO, B, 0, stream>>>(ocur, olist, row, col, ew, deg, h2, out);
}

// Round 10
// 363.192 us; speedup vs baseline: 2.6255x; 1.0723x over previous
//
#include <hip/hip_runtime.h>
#include <hip/hip_bf16.h>

#define N_NODES 100000
#define N_EDGES 3200000
#define FEAT 256
#define HIDDEN 32
#define EMBED 16
#define NPB 128                                // nodes per bin
#define NBIN ((N_NODES + NPB - 1) / NPB)       // 782
#define NBLK 1024                              // partition blocks
#define EPB ((N_EDGES + NBLK - 1) / NBLK)      // 3125 edges per block
#define CAPB 4608                              // bin capacity (mean 4096 + 8 sigma)
#define OCAP 8192                              // overflow list capacity
#define GR 128                                 // gemm1 tile rows
#define GS 68                                  // LDS row stride (floats)
#define G1N 32                                 // nodes per gather1 block
#define G1CAP 2048                             // LDS entries (window mean 1024, sigma 32)
#define G2N 64                                 // nodes per gather2 block
#define G2CAP 3072                             // LDS entries (window mean 2048, sigma 45)

// ---------------- zero: binCnt, overflow cursor ----------------
__global__ void k_zero(int* __restrict__ binCnt, int* __restrict__ ocur) {
    int i = blockIdx.x * blockDim.x + threadIdx.x;
    if (i < NBIN) binCnt[i] = 0;
    if (i == 0) *ocur = 0;
}

// ---------------- partition edges into node-range bins ----------------
__global__ __launch_bounds__(256) void k_part(
        const int* __restrict__ row, const int* __restrict__ col,
        const float* __restrict__ ew, int* __restrict__ binCnt,
        int2* __restrict__ binned, int* __restrict__ ocur, int* __restrict__ olist) {
    __shared__ int sh[NBIN];   // hist, then base
    __shared__ int sc[NBIN];   // running cursor
    const int tid = threadIdx.x;
    for (int i = tid; i < NBIN; i += 256) sh[i] = 0;
    __syncthreads();
    const int e0 = blockIdx.x * EPB, e1 = min(e0 + EPB, N_EDGES);
    for (int e = e0 + tid; e < e1; e += 256) atomicAdd(&sh[col[e] >> 7], 1);
    __syncthreads();
    for (int i = tid; i < NBIN; i += 256) {
        int n = sh[i];
        sh[i] = (n > 0) ? atomicAdd(&binCnt[i], n) : 0;
        sc[i] = 0;
    }
    __syncthreads();
    for (int e = e0 + tid; e < e1; e += 256) {
        int c = col[e], b = c >> 7;
        int s = sh[b] + atomicAdd(&sc[b], 1);
        if (s < CAPB)
            binned[(size_t)b * CAPB + s] =
                make_int2(((c & (NPB - 1)) << 17) | row[e], __float_as_int(ew[e]));
        else { int p = atomicAdd(ocur, 1); if (p < OCAP) olist[p] = e; }
    }
}

// ---------------- per-bin: group by node in-place, deg, off2 ----------------
__global__ __launch_bounds__(256) void k_build(
        const int* __restrict__ binCnt, int2* __restrict__ binned,
        float* __restrict__ deg, int2* __restrict__ off2) {
    __shared__ int2 se[CAPB];
    __shared__ int scnt[NPB], spfx[NPB], scur[NPB];
    __shared__ float sdeg[NPB];
    const int bin = blockIdx.x, tid = threadIdx.x;
    const int n = min(binCnt[bin], CAPB);
    const size_t base = (size_t)bin * CAPB;

    for (int i = tid; i < NPB; i += 256) { scnt[i] = 0; sdeg[i] = 0.f; }
    __syncthreads();
    for (int i = tid; i < n; i += 256) {
        int2 v = binned[base + i];
        se[i] = v;
        int lc = v.x >> 17;
        atomicAdd(&scnt[lc], 1);
        atomicAdd(&sdeg[lc], __int_as_float(v.y));
    }
    __syncthreads();
    if (tid < NPB) spfx[tid] = scnt[tid];
    __syncthreads();
    for (int d = 1; d < NPB; d <<= 1) {
        int t = 0;
        if (tid < NPB && tid >= d) t = spfx[tid - d];
        __syncthreads();
        if (tid < NPB) spfx[tid] += t;
        __syncthreads();
    }
    if (tid < NPB) {
        int ex = spfx[tid] - scnt[tid];
        scur[tid] = ex;
        int node = bin * NPB + tid;
        if (node < N_NODES) {
            off2[node] = make_int2((int)base + ex, scnt[tid]);
            deg[node] = sdeg[tid] + 1.0f;  // + self loop
        }
    }
    __syncthreads();
    for (int i = tid; i < n; i += 256) {
        int2 v = se[i];
        int lc = v.x >> 17;
        int s = atomicAdd(&scur[lc], 1);   // LDS atomic
        binned[base + s] = make_int2(v.x & 0x1FFFF, v.y);  // {src, ew}
    }
}

__global__ void k_degover(const int* __restrict__ ocur, const int* __restrict__ olist,
                          const int* __restrict__ col, const float* __restrict__ ew,
                          float* __restrict__ deg) {
    int p = blockIdx.x * blockDim.x + threadIdx.x;
    int n = min(*ocur, OCAP);
    if (p < n) { int e = olist[p]; unsafeAtomicAdd(&deg[col[e]], ew[e]); }
}

__global__ void k_dis(float* __restrict__ deg) {
    int i = blockIdx.x * blockDim.x + threadIdx.x;
    if (i < N_NODES) {
        float d = deg[i];
        deg[i] = (d > 0.0f) ? rsqrtf(d) : 0.0f;
    }
}

// ---------------- fold dis[src] into csr weights in-place ----------------
__global__ void k_wnorm(const int* __restrict__ binCnt, int2* __restrict__ csr,
                        const float* __restrict__ dis) {
    int bin = blockIdx.x;
    int n = min(binCnt[bin], CAPB);
    size_t base = (size_t)bin * CAPB;
    for (int i = threadIdx.x; i < n; i += 256) {
        int2 v = csr[base + i];
        float w = __int_as_float(v.y) * dis[v.x];
        csr[base + i] = make_int2(v.x, __float_as_int(w));
    }
}

// ---------------- layer 1 GEMM: h = x @ W1^T (unchanged from R9) ----------------
__global__ __launch_bounds__(256) void k_gemm1(
        const float* __restrict__ x, const float* __restrict__ W1,
        float* __restrict__ h) {
    __shared__ float sx[GR][GS];
    __shared__ float sw[HIDDEN][GS];

    const int tid = threadIdx.x;
    const size_t base = (size_t)blockIdx.x * GR;
    const float4* x4 = (const float4*)x;
    const float4* w4 = (const float4*)W1;

    const int r0 = tid >> 3;
    const int c0 = tid & 7;
    float acc[4][4] = {};

#pragma unroll
    for (int p = 0; p < 4; ++p) {
        for (int i = tid; i < GR * 16; i += 256) {
            int r = i >> 4, kq = i & 15;
            float4 v = make_float4(0.f, 0.f, 0.f, 0.f);
            if (base + r < N_NODES) v = x4[(base + r) * 64 + p * 16 + kq];
            *(float4*)&sx[r][kq * 4] = v;
        }
        for (int i = tid; i < HIDDEN * 16; i += 256) {
            int f = i >> 4, kq = i & 15;
            *(float4*)&sw[f][kq * 4] = w4[f * 64 + p * 16 + kq];
        }
        __syncthreads();

#pragma unroll 4
        for (int kq = 0; kq < 16; ++kq) {
            float4 xa[4], wv[4];
#pragma unroll
            for (int m = 0; m < 4; ++m) xa[m] = *(const float4*)&sx[r0 + 32 * m][kq * 4];
#pragma unroll
            for (int j = 0; j < 4; ++j) wv[j] = *(const float4*)&sw[c0 + 8 * j][kq * 4];
#pragma unroll
            for (int m = 0; m < 4; ++m)
#pragma unroll
                for (int j = 0; j < 4; ++j)
                    acc[m][j] += xa[m].x * wv[j].x + xa[m].y * wv[j].y +
                                 xa[m].z * wv[j].z + xa[m].w * wv[j].w;
        }
        __syncthreads();
    }

#pragma unroll
    for (int m = 0; m < 4; ++m) {
        size_t r = base + r0 + 32 * m;
        if (r < N_NODES) {
#pragma unroll
            for (int j = 0; j < 4; ++j) h[r * HIDDEN + c0 + 8 * j] = acc[m][j];
        }
    }
}

// ---- layer 1 gather: LDS-staged csr window (32 contiguous nodes) ----
// A 32-node window's csr segments are contiguous (grouped per-bin CSR),
// so stage once coalesced; 8 feature-threads/node read LDS broadcasts.
__global__ __launch_bounds__(256) void k_gather1(
        const int2* __restrict__ off2, const int2* __restrict__ csr,
        const float* __restrict__ h, const float* __restrict__ dis,
        const float* __restrict__ b1, float* __restrict__ out1) {
    __shared__ int2 sc[G1CAP];
    __shared__ int s_start, s_n;
    const int tid = threadIdx.x;
    const int node0 = blockIdx.x * G1N;           // 100000 = 32*3125 exact
    if (tid == 0) {
        int2 a = off2[node0];
        int2 b = off2[node0 + G1N - 1];
        s_start = a.x;
        s_n = b.x + b.y - a.x;
    }
    __syncthreads();
    const int start = s_start, n = s_n;
    const bool fit = (n <= G1CAP);
    if (fit) for (int i = tid; i < n; i += 256) sc[i] = csr[start + i];
    __syncthreads();

    const int node = node0 + (tid >> 3);
    const int og = tid & 7;
    float d = dis[node];
    float d2 = d * d;
    float4 self = *(const float4*)(h + (size_t)node * HIDDEN + og * 4);
    float4 bv = *(const float4*)(b1 + og * 4);
    float4 acc = make_float4(0.f, 0.f, 0.f, 0.f);

    int2 o = off2[node];
    for (int j = 0; j < o.y; ++j) {
        int2 v = fit ? sc[o.x - start + j] : csr[o.x + j];
        float w = __int_as_float(v.y);
        const float4 hv = *(const float4*)(h + (size_t)v.x * HIDDEN + og * 4);
        acc.x += hv.x * w; acc.y += hv.y * w; acc.z += hv.z * w; acc.w += hv.w * w;
    }
    *(float4*)(out1 + (size_t)node * HIDDEN + og * 4) =
        make_float4(acc.x * d + self.x * d2 + bv.x, acc.y * d + self.y * d2 + bv.y,
                    acc.z * d + self.z * d2 + bv.z, acc.w * d + self.w * d2 + bv.w);
}

__global__ void k_over1(const int* __restrict__ ocur, const int* __restrict__ olist,
                        const int* __restrict__ row, const int* __restrict__ col,
                        const float* __restrict__ ew, const float* __restrict__ dis,
                        const float* __restrict__ h, float* __restrict__ out1) {
    int p = blockIdx.x * blockDim.x + threadIdx.x;
    int n = min(*ocur, OCAP);
    if (p < n) {
        int e = olist[p];
        int r = row[e], c = col[e];
        float w = dis[r] * ew[e] * dis[c];
        for (int f = 0; f < HIDDEN; ++f)
            unsafeAtomicAdd(&out1[(size_t)c * HIDDEN + f], h[(size_t)r * HIDDEN + f] * w);
    }
}

// ---------------- layer 2 GEMM: h2 = relu(out1) @ W2^T ----------------
__global__ void k_gemm2(const float* __restrict__ out1, const float* __restrict__ W2,
                        float* __restrict__ h2) {
    int t = blockIdx.x * blockDim.x + threadIdx.x;
    int i = t >> 4;
    if (i >= N_NODES) return;
    int f = t & 15;
    const float* r = out1 + (size_t)i * HIDDEN;
    const float* w = W2 + f * HIDDEN;
    float acc = 0.f;
#pragma unroll
    for (int k = 0; k < HIDDEN; ++k) acc += fmaxf(r[k], 0.f) * w[k];
    h2[(size_t)i * EMBED + f] = acc;
}

// ---- layer 2 gather: LDS-staged csr window (64 contiguous nodes) ----
__global__ __launch_bounds__(256) void k_gather2(
        const int2* __restrict__ off2, const int2* __restrict__ csr,
        const float* __restrict__ h2, const float* __restrict__ dis,
        const float* __restrict__ b2, float* __restrict__ out) {
    __shared__ int2 sc[G2CAP];
    __shared__ int s_start, s_n;
    const int tid = threadIdx.x;
    const int node0 = blockIdx.x * G2N;
    const int lastn = min(node0 + G2N, N_NODES) - 1;
    if (tid == 0) {
        int2 a = off2[node0];
        int2 b = off2[lastn];
        s_start = a.x;
        s_n = b.x + b.y - a.x;
    }
    __syncthreads();
    const int start = s_start, n = s_n;
    const bool fit = (n <= G2CAP);
    if (fit) for (int i = tid; i < n; i += 256) sc[i] = csr[start + i];
    __syncthreads();

    const int node = node0 + (tid >> 2);
    const int og = tid & 3;
    if (node >= N_NODES) return;
    float d = dis[node];
    float d2 = d * d;
    float4 self = *(const float4*)(h2 + (size_t)node * EMBED + og * 4);
    float4 bv = *(const float4*)(b2 + og * 4);
    float4 acc = make_float4(0.f, 0.f, 0.f, 0.f);

    int2 o = off2[node];
    for (int j = 0; j < o.y; ++j) {
        int2 v = fit ? sc[o.x - start + j] : csr[o.x + j];
        float w = __int_as_float(v.y);
        const float4 hv = *(const float4*)(h2 + (size_t)v.x * EMBED + og * 4);
        acc.x += hv.x * w; acc.y += hv.y * w; acc.z += hv.z * w; acc.w += hv.w * w;
    }
    *(float4*)(out + (size_t)node * EMBED + og * 4) =
        make_float4(acc.x * d + self.x * d2 + bv.x, acc.y * d + self.y * d2 + bv.y,
                    acc.z * d + self.z * d2 + bv.z, acc.w * d + self.w * d2 + bv.w);
}

__global__ void k_over2(const int* __restrict__ ocur, const int* __restrict__ olist,
                        const int* __restrict__ row, const int* __restrict__ col,
                        const float* __restrict__ ew, const float* __restrict__ dis,
                        const float* __restrict__ h2, float* __restrict__ out) {
    int p = blockIdx.x * blockDim.x + threadIdx.x;
    int n = min(*ocur, OCAP);
    if (p < n) {
        int e = olist[p];
        int r = row[e], c = col[e];
        float w = dis[r] * ew[e] * dis[c];
        for (int f = 0; f < EMBED; ++f)
            unsafeAtomicAdd(&out[(size_t)c * EMBED + f], h2[(size_t)r * EMBED + f] * w);
    }
}

extern "C" void kernel_launch(void* const* d_in, const int* in_sizes, int n_in,
                              void* d_out, int out_size, void* d_ws, size_t ws_size,
                              hipStream_t stream) {
    const float* x  = (const float*)d_in[0];
    const int*   ei = (const int*)d_in[1];  // [2, E] int32
    const float* ew = (const float*)d_in[2];
    const float* W1 = (const float*)d_in[3];
    const float* b1 = (const float*)d_in[4];
    const float* W2 = (const float*)d_in[5];
    const float* b2 = (const float*)d_in[6];
    float* out = (float*)d_out;

    const int* row = ei;            // source
    const int* col = ei + N_EDGES;  // target

    int2*  off2   = (int2*)d_ws;
    int2*  binned = off2 + N_NODES;
    float* deg    = (float*)(binned + (size_t)NBIN * CAPB);
    int*   binCnt = (int*)(deg + N_NODES);
    int*   ocur   = binCnt + NBIN;
    int*   olist  = ocur + 2;
    size_t off_i  = (size_t)(olist + OCAP - (int*)d_ws);
    off_i = (off_i + 3) & ~(size_t)3;            // 16B align
    float* h    = (float*)d_ws + off_i;
    float* out1 = h + (size_t)N_NODES * HIDDEN;
    float* h2   = h;  // alias: h dead after k_gather1

    const int B = 256;
    const int gN = (N_NODES + B - 1) / B;
    const int gO = (OCAP + B - 1) / B;

    k_zero<<<(NBIN + B - 1) / B, B, 0, stream>>>(binCnt, ocur);
    k_part<<<NBLK, B, 0, stream>>>(row, col, ew, binCnt, binned, ocur, olist);
    k_build<<<NBIN, B, 0, stream>>>(binCnt, binned, deg, off2);
    k_degover<<<gO, B, 0, stream>>>(ocur, olist, col, ew, deg);
    k_dis<<<gN, B, 0, stream>>>(deg);
    k_wnorm<<<NBIN, B, 0, stream>>>(binCnt, binned, deg);
    k_gemm1<<<(N_NODES + GR - 1) / GR, B, 0, stream>>>(x, W1, h);
    k_gather1<<<N_NODES / G1N, B, 0, stream>>>(off2, binned, h, deg, b1, out1);
    k_over1<<<gO, B, 0, stream>>>(ocur, olist, row, col, ew, deg, h, out1);
    k_gemm2<<<(N_NODES * 16 + B - 1) / B, B, 0, stream>>>(out1, W2, h2);
    k_gather2<<<(N_NODES + G2N - 1) / G2N, B, 0, stream>>>(off2, binned, h2, deg, b2, out);
    k_over2<<<gO, B, 0, stream>>>(ocur, olist, row, col, ew, deg, h2, out);
}